// Round 2
// baseline (67.924 us; speedup 1.0000x reference)
//
#include <hip/hip_runtime.h>
#include <stdint.h>

// Maj3FC: out[b,c] = 2.25 * sum_g sign( sum_{k<3} sign(x[b,3g+k])*sign(w[c,3g+k]) )
// B=512, C_IN=1536, C_OUT=512, G=512 groups of 3. Exact integer math -> absmax 0.
//
// R8: wave-uniform x operand. R7 was DS-bound (48 ds_read_b128 per output:
// both operands from LDS). Now each wave owns one b-row: x comes in via
// uniform (scalar-path) loads -- 16B per instr, SGPR operands free in VALU --
// and only w flows through LDS: 24 b128/output (2x DS cut, ~1.9us/CU floor).
// w is packed chunk-TRANSPOSED in global (pwT[chunk][c]) so lane=c reads
// swT[u][lane] = linear b128 (full-speed, conflict-free) and staging is
// coalesced. Full-K per thread: no split-K combine, one barrier, coalesced
// 256B/wave output stores. Block = 4 waves = 4b x 64c; grid 8x128 = 1024
// blocks -> 4 blocks/CU -> 16 waves/CU; LDS 24KB.
//
// Bit-plane format (R7): per 32-group slice, 6 plane words P0,P1,P2,N0,N1,N2.
// Chunk = 64 groups = 3 uint4: u0=(P0a,P0b,P1a,P1b) u1=(P2a,P2b,N0a,N0b)
// u2=(N1a,N1b,N2a,N2b); a = first 32 groups, b = last 32.

#define CIN     1536
#define B_DIM   512
#define COUT    512
#define GROUPS  512   // CIN/3 exact
#define ROW_U4  24    // uint4 per packed row (8 chunks x 3)

// ---------------- pack kernel ----------------
// 64 blocks x 256 threads. t -> (row = t>>4, slice = t&15): packs 96
// consecutive floats (32 groups) into 6 plane words. Reads coalesced across
// the 16 threads of a row. x rows -> row-major px; w rows -> transposed pwT.
__global__ __launch_bounds__(256) void pack_kernel(
    const float* __restrict__ x, const float* __restrict__ w,
    uint32_t* __restrict__ px, uint32_t* __restrict__ pwT) {
  const int t = blockIdx.x * 256 + threadIdx.x;  // 0..16383
  const int row = t >> 4;                        // 0..1023
  const int slice = t & 15;
  const bool isx = row < B_DIM;
  const float* src = isx ? (x + (size_t)row * CIN)
                         : (w + (size_t)(row - B_DIM) * CIN);
  const float4* s4 = (const float4*)(src + slice * 96);

  unsigned P0 = 0, P1 = 0, P2 = 0, N0 = 0, N1 = 0, N2 = 0;
  #pragma unroll
  for (int i = 0; i < 8; i++) {
    float4 q0 = s4[3 * i], q1 = s4[3 * i + 1], q2 = s4[3 * i + 2];
    float f[12] = {q0.x, q0.y, q0.z, q0.w, q1.x, q1.y, q1.z, q1.w,
                   q2.x, q2.y, q2.z, q2.w};
    #pragma unroll
    for (int g = 0; g < 4; g++) {
      const int bit = i * 4 + g;
      float a = f[3 * g], b = f[3 * g + 1], c = f[3 * g + 2];
      P0 |= (a > 0.0f ? 1u : 0u) << bit;
      N0 |= (a < 0.0f ? 1u : 0u) << bit;
      P1 |= (b > 0.0f ? 1u : 0u) << bit;
      N1 |= (b < 0.0f ? 1u : 0u) << bit;
      P2 |= (c > 0.0f ? 1u : 0u) << bit;
      N2 |= (c < 0.0f ? 1u : 0u) << bit;
    }
  }
  const int h = slice & 1, ch = slice >> 1;
  if (isx) {
    // row-major: dword row*96 + ch*12 + plane offsets
    uint32_t* d = px + (size_t)row * 96 + ch * 12;
    d[h]     = P0;  d[2 + h]  = P1;  d[4 + h]  = P2;
    d[6 + h] = N0;  d[8 + h]  = N1;  d[10 + h] = N2;
  } else {
    // transposed: pwT is uint4[24][512]; uint4 u = 3*ch + k at dword u*2048 + r*4
    const int r = row - B_DIM;
    uint32_t* base = pwT + (size_t)(3 * ch) * 2048 + r * 4;
    base[h]        = P0;  base[2 + h]        = P1;   // u0: P0a P0b P1a P1b
    base[2048 + h] = P2;  base[2048 + 2 + h] = N0;   // u1: P2a P2b N0a N0b
    base[4096 + h] = N1;  base[4096 + 2 + h] = N2;   // u2: N1a N1b N2a N2b
  }
}

// ---------------- main kernel ----------------
// 32 groups per call: cp = #(+1 products), cn = #(-1); contribution
// (cp>cn)+(cp>=cn) = sign+1. sum(sign) = acc_total - 512.
__device__ __forceinline__ void maj32(
    unsigned xp0, unsigned xp1, unsigned xp2,
    unsigned xn0, unsigned xn1, unsigned xn2,
    unsigned wp0, unsigned wp1, unsigned wp2,
    unsigned wn0, unsigned wn1, unsigned wn2,
    int& acc) {
  unsigned pos0 = (xp0 & wp0) | (xn0 & wn0);
  unsigned pos1 = (xp1 & wp1) | (xn1 & wn1);
  unsigned pos2 = (xp2 & wp2) | (xn2 & wn2);
  unsigned neg0 = (xp0 & wn0) | (xn0 & wp0);
  unsigned neg1 = (xp1 & wn1) | (xn1 & wp1);
  unsigned neg2 = (xp2 & wn2) | (xn2 & wp2);
  unsigned sa  = pos0 ^ pos1;
  unsigned cp0 = sa ^ pos2;
  unsigned cp1 = (pos0 & pos1) | (pos2 & sa);
  unsigned sb  = neg0 ^ neg1;
  unsigned cn0 = sb ^ neg2;
  unsigned cn1 = (neg0 & neg1) | (neg2 & sb);
  unsigned nh = ~cn1;
  unsigned nl = ~cn0;
  unsigned hi = cp1 & nh;
  unsigned eq = ~(cp1 ^ cn1);
  unsigned gt = hi | (eq & (cp0 & nl));
  unsigned ge = hi | (eq & (cp0 | nl));
  acc += __popc(gt) + __popc(ge);
}

// Block: 256 threads = 4 waves; wave -> one b (uniform x row), lane -> one c.
// grid = (COUT/64, B_DIM/4) = (8, 128) = 1024 blocks -> 16 waves/CU.
__global__ __launch_bounds__(256, 4) void maj3_kernel(
    const uint4* __restrict__ px, const uint4* __restrict__ pwT,
    float* __restrict__ out) {
  __shared__ __align__(16) uint4 swT[24][64];  // 24 KB, chunk-major, lane=c

  const int tid = threadIdx.x;
  const int c0 = blockIdx.x * 64;
  const int b0 = blockIdx.y * 4;

  // stage w tile: global transposed layout -> coalesced reads, linear LDS
  #pragma unroll
  for (int it = 0; it < 6; ++it) {
    int i = it * 256 + tid;                      // 0..1535 = u*64 + r
    ((uint4*)swT)[i] = pwT[(size_t)(i >> 6) * 512 + c0 + (i & 63)];
  }
  __syncthreads();

  const int lane = tid & 63;
  const int bw = __builtin_amdgcn_readfirstlane(b0 + (tid >> 6));
  const uint4* xrow = px + (size_t)bw * ROW_U4;  // uniform per wave

  int acc = 0;
  #pragma unroll
  for (int j = 0; j < 8; ++j) {
    uint4 xa0 = xrow[3 * j], xa1 = xrow[3 * j + 1], xa2 = xrow[3 * j + 2];
    uint4 wb0 = swT[3 * j][lane];
    uint4 wb1 = swT[3 * j + 1][lane];
    uint4 wb2 = swT[3 * j + 2][lane];
    // slice a: groups [64j, 64j+32)
    maj32(xa0.x, xa0.z, xa1.x, xa1.z, xa2.x, xa2.z,
          wb0.x, wb0.z, wb1.x, wb1.z, wb2.x, wb2.z, acc);
    // slice b: groups [64j+32, 64j+64)
    maj32(xa0.y, xa0.w, xa1.y, xa1.w, xa2.y, xa2.w,
          wb0.y, wb0.w, wb1.y, wb1.w, wb2.y, wb2.w, acc);
  }

  // wave-contiguous 256B store
  out[(size_t)bw * COUT + c0 + lane] = 2.25f * (float)(acc - GROUPS);
}

extern "C" void kernel_launch(void* const* d_in, const int* in_sizes, int n_in,
                              void* d_out, int out_size, void* d_ws, size_t ws_size,
                              hipStream_t stream) {
  const float* x = (const float*)d_in[0];   // [512, 1536]
  const float* w = (const float*)d_in[1];   // [512, 1536]
  float* out = (float*)d_out;               // [512, 512]

  uint32_t* px  = (uint32_t*)d_ws;                 // [512][96] dwords = 192 KB
  uint32_t* pwT = px + (size_t)B_DIM * 96;         // [24][512] uint4  = 192 KB

  pack_kernel<<<64, 256, 0, stream>>>(x, w, px, pwT);

  dim3 grid(COUT / 64, B_DIM / 4);
  maj3_kernel<<<grid, 256, 0, stream>>>((const uint4*)px, (const uint4*)pwT, out);
}

// Round 3
// 64.635 us; speedup vs baseline: 1.0509x; 1.0509x over previous
//
#include <hip/hip_runtime.h>
#include <stdint.h>

// Maj3FC: out[b,c] = 2.25 * sum_g sign( sum_{k<3} sign(x[b,3g+k])*sign(w[c,3g+k]) )
// B=512, C_IN=1536, C_OUT=512, G=512 groups of 3. Exact integer math -> absmax 0.
//
// R9: ballot pack + R7 maj3 (rollback of R8's wave-uniform maj3, which
// regressed). Evidence: R7 (2.8x VALU cut) -3.5us, R8 (2x DS cut) +1.4us =>
// maj3 isn't the dominant residual; pack was (1 wave/CU, ~500 serial VALU
// bit-insert ops/thread, full drain before maj3 starts).
// New pack: lane = group, one 12B load/lane, __ballot(v>0)/__ballot(v<0)
// per element-plane emits the 64-bit plane words directly: 6 cmp + 6 ballot
// per 64 groups (was ~170 ops). 512 blocks -> 2048 waves -> 8 waves/CU.
// Ballot lo/hi halves match the chunk layout exactly.
//
// Bit-plane format (R7): chunk = 64 groups = 3 uint4:
//   u4[0]=(P0a,P0b,P1a,P1b) u4[1]=(P2a,P2b,N0a,N0b) u4[2]=(N1a,N1b,N2a,N2b)
// a = low 32 groups (ballot lo), b = high 32 (ballot hi); Pk/Nk = sign planes
// of element k in the group. Row = 8 chunks = 96 dwords.

#define CIN     1536
#define B_DIM   512
#define COUT    512
#define GROUPS  512   // CIN/3 exact
#define ROW_U4  24    // uint4 per packed row
#define XSTRIDE 25    // LDS row stride in uint4 (100 dwords; 100%32=4 -> conflict-free)

// ---------------- pack kernel ----------------
// 512 blocks x 256 threads = 2048 waves. Wave gw -> (row = gw>>1, half = gw&1),
// handles chunks [4*half, 4*half+4). Lane = group within chunk.
__global__ __launch_bounds__(256) void pack_kernel(
    const float* __restrict__ x, const float* __restrict__ w,
    uint32_t* __restrict__ packed) {
  const int gw   = blockIdx.x * 4 + (threadIdx.x >> 6);  // 0..2047
  const int lane = threadIdx.x & 63;
  const int row  = gw >> 1;
  const int half = gw & 1;
  const float* src = (row < B_DIM) ? (x + (size_t)row * CIN)
                                   : (w + (size_t)(row - B_DIM) * CIN);
  const int j = lane >> 1;          // which plane word (0..5) this lane stores
  const int hi = lane & 1;          // lo/hi half of the u64

  #pragma unroll
  for (int si = 0; si < 4; si++) {
    const int s = 4 * half + si;    // chunk index 0..7
    // group g = 64*s + lane: floats [3g, 3g+3)
    const float3 f = ((const float3*)src)[64 * s + lane];
    unsigned long long P0 = __ballot(f.x > 0.0f);
    unsigned long long N0 = __ballot(f.x < 0.0f);
    unsigned long long P1 = __ballot(f.y > 0.0f);
    unsigned long long N1 = __ballot(f.y < 0.0f);
    unsigned long long P2 = __ballot(f.z > 0.0f);
    unsigned long long N2 = __ballot(f.z < 0.0f);
    // dwords 0..11 of the chunk: P0lo P0hi P1lo P1hi P2lo P2hi N0lo N0hi N1lo N1hi N2lo N2hi
    unsigned h0 = hi ? (unsigned)(P0 >> 32) : (unsigned)P0;
    unsigned h1 = hi ? (unsigned)(P1 >> 32) : (unsigned)P1;
    unsigned h2 = hi ? (unsigned)(P2 >> 32) : (unsigned)P2;
    unsigned h3 = hi ? (unsigned)(N0 >> 32) : (unsigned)N0;
    unsigned h4 = hi ? (unsigned)(N1 >> 32) : (unsigned)N1;
    unsigned h5 = hi ? (unsigned)(N2 >> 32) : (unsigned)N2;
    unsigned v01 = (j == 1) ? h1 : h0;
    unsigned v23 = (j == 3) ? h3 : h2;
    unsigned v45 = (j == 5) ? h5 : h4;
    unsigned val = (j < 2) ? v01 : ((j < 4) ? v23 : v45);
    if (lane < 12) packed[(size_t)row * 96 + s * 12 + lane] = val;
  }
}

// ---------------- main kernel (R7, best measured) ----------------
// 32 groups per call: cp = #(+1 products), cn = #(-1); contribution
// (cp>cn)+(cp>=cn) = sign+1. sum(sign) over 512 groups = acc_total - 512.
__device__ __forceinline__ void maj32(
    unsigned xp0, unsigned xp1, unsigned xp2,
    unsigned xn0, unsigned xn1, unsigned xn2,
    unsigned wp0, unsigned wp1, unsigned wp2,
    unsigned wn0, unsigned wn1, unsigned wn2,
    int& acc) {
  unsigned pos0 = (xp0 & wp0) | (xn0 & wn0);
  unsigned pos1 = (xp1 & wp1) | (xn1 & wn1);
  unsigned pos2 = (xp2 & wp2) | (xn2 & wn2);
  unsigned neg0 = (xp0 & wn0) | (xn0 & wp0);
  unsigned neg1 = (xp1 & wn1) | (xn1 & wp1);
  unsigned neg2 = (xp2 & wn2) | (xn2 & wp2);
  unsigned sa  = pos0 ^ pos1;
  unsigned cp0 = sa ^ pos2;
  unsigned cp1 = (pos0 & pos1) | (pos2 & sa);
  unsigned sb  = neg0 ^ neg1;
  unsigned cn0 = sb ^ neg2;
  unsigned cn1 = (neg0 & neg1) | (neg2 & sb);
  unsigned nh = ~cn1;
  unsigned nl = ~cn0;
  unsigned hi = cp1 & nh;
  unsigned eq = ~(cp1 ^ cn1);
  unsigned gt = hi | (eq & (cp0 & nl));
  unsigned ge = hi | (eq & (cp0 | nl));
  acc += __popc(gt) + __popc(ge);
}

// 16(b) x 8(c) tile, 256 threads, 128 outputs, split-K by 2.
// grid = (64, 32) = 2048 blocks -> 8 blocks/CU -> 32 waves/CU.
// LDS = (16+8)*25*16 + 128*4 = 10.1 KB.
__global__ __launch_bounds__(256, 8) void maj3_kernel(
    const uint4* __restrict__ px, const uint4* __restrict__ pw,
    float* __restrict__ out) {
  __shared__ __align__(16) uint4 sx[16][XSTRIDE];
  __shared__ __align__(16) uint4 sw[8][XSTRIDE];
  __shared__ int comb[128];

  const int b0 = blockIdx.y * 16;
  const int c0 = blockIdx.x * 8;
  const int tid = threadIdx.x;

  // packed rows are dense in global (24 uint4/row); scatter to stride-25 LDS
  const uint4* gx = px + (size_t)b0 * ROW_U4;
  const uint4* gw = pw + (size_t)c0 * ROW_U4;
  #pragma unroll
  for (int i = tid; i < 16 * ROW_U4; i += 256) {
    int r = i / ROW_U4, wd = i - r * ROW_U4;
    sx[r][wd] = gx[i];
  }
  if (tid < 8 * ROW_U4) {
    int r = tid / ROW_U4, wd = tid - r * ROW_U4;
    sw[r][wd] = gw[tid];
  }
  __syncthreads();

  const int o  = tid & 127;  // output index within tile
  const int tx = o & 7;      // c within tile
  const int ty = o >> 3;     // b within tile
  const int h  = tid >> 7;   // K-half: chunks [4h, 4h+4)

  const uint4* xr = &sx[ty][h * 12];
  const uint4* wr = &sw[tx][h * 12];

  int acc = 0;
  #pragma unroll
  for (int i = 0; i < 4; i++) {
    uint4 a0 = xr[3 * i], a1 = xr[3 * i + 1], a2 = xr[3 * i + 2];
    uint4 b0v = wr[3 * i], b1 = wr[3 * i + 1], b2 = wr[3 * i + 2];
    // slice a: groups [64i, 64i+32) of this half
    maj32(a0.x, a0.z, a1.x, a1.z, a2.x, a2.z,
          b0v.x, b0v.z, b1.x, b1.z, b2.x, b2.z, acc);
    // slice b: groups [64i+32, 64i+64)
    maj32(a0.y, a0.w, a1.y, a1.w, a2.y, a2.w,
          b0v.y, b0v.w, b1.y, b1.w, b2.y, b2.w, acc);
  }

  if (h == 1) comb[o] = acc;
  __syncthreads();
  if (h == 0) {
    // acc_total = sum over 512 groups of (sign+1); sum(sign) = acc_total - 512
    int total = acc + comb[o];
    out[(size_t)(b0 + ty) * COUT + (c0 + tx)] = 2.25f * (float)(total - GROUPS);
  }
}

extern "C" void kernel_launch(void* const* d_in, const int* in_sizes, int n_in,
                              void* d_out, int out_size, void* d_ws, size_t ws_size,
                              hipStream_t stream) {
  const float* x = (const float*)d_in[0];   // [512, 1536]
  const float* w = (const float*)d_in[1];   // [512, 1536]
  float* out = (float*)d_out;               // [512, 512]

  uint32_t* packed = (uint32_t*)d_ws;       // [1024][96] dwords = 384 KB
  const uint4* px = (const uint4*)packed;                        // rows 0..511 (x)
  const uint4* pw = (const uint4*)(packed + (size_t)B_DIM * 96); // rows 512..1023 (w)

  pack_kernel<<<512, 256, 0, stream>>>(x, w, packed);

  dim3 grid(COUT / 8, B_DIM / 16);
  maj3_kernel<<<grid, 256, 0, stream>>>(px, pw, out);
}

// Round 4
// 64.167 us; speedup vs baseline: 1.0586x; 1.0073x over previous
//
#include <hip/hip_runtime.h>
#include <stdint.h>

// Maj3FC: out[b,c] = 2.25 * sum_g sign( sum_{k<3} sign(x[b,3g+k])*sign(w[c,3g+k]) )
// B=512, C_IN=1536, C_OUT=512, G=512 groups of 3. Exact integer math -> absmax 0.
//
// R10: register-blocked maj3 (2b x 2c per thread) + R9 ballot pack.
// Ledger: R7 VALU-cut -3.5us, R8 wave-uniform-x +1.4us (occupancy loss),
// R9 ballot-pack -1.9us. Residual over the ~41us harness fill is maj3
// (~9-12us, DS-floor 3.8us: 24 ds_read_b128 per output-half, both operands
// re-read per output). Fix: 2x2 micro-tile per thread -> 4 outputs share
// each LDS fetch: DS/output 48 -> 24 b128 (floor 1.9us), VALU/output
// unchanged, 4 independent acc chains + 12 in-flight b128 per thread.
// Tile 16x16, split-K 4 (wave = K-quarter: 2 chunks), 256 thr, grid 32x32
// = 1024 blocks -> 4 blocks/CU -> 16 waves/CU. LDS 16.9 KB. Row stride 25
// uint4: paired-row reads land on banks 8*t2b%32 -> 2-way = free (m136).
// Stage: thread -> (row tid>>3, 3 consecutive uint4), branch-free, 384B/row
// contiguous, no divides.
//
// Bit-plane format (R7): chunk = 64 groups = 3 uint4:
//   u4[0]=(P0a,P0b,P1a,P1b) u4[1]=(P2a,P2b,N0a,N0b) u4[2]=(N1a,N1b,N2a,N2b)
// a = low 32 groups (ballot lo), b = high 32 (ballot hi). Row = 8 chunks.

#define CIN     1536
#define B_DIM   512
#define COUT    512
#define GROUPS  512   // CIN/3 exact
#define ROW_U4  24    // uint4 per packed row
#define XSTRIDE 25    // LDS row stride in uint4 (100 dwords)

// ---------------- pack kernel (R9, measured win) ----------------
// 512 blocks x 256 threads = 2048 waves. Wave gw -> (row = gw>>1, half = gw&1),
// handles chunks [4*half, 4*half+4). Lane = group within chunk.
__global__ __launch_bounds__(256) void pack_kernel(
    const float* __restrict__ x, const float* __restrict__ w,
    uint32_t* __restrict__ packed) {
  const int gw   = blockIdx.x * 4 + (threadIdx.x >> 6);  // 0..2047
  const int lane = threadIdx.x & 63;
  const int row  = gw >> 1;
  const int half = gw & 1;
  const float* src = (row < B_DIM) ? (x + (size_t)row * CIN)
                                   : (w + (size_t)(row - B_DIM) * CIN);
  const int j = lane >> 1;          // which plane word (0..5) this lane stores
  const int hi = lane & 1;          // lo/hi half of the u64

  #pragma unroll
  for (int si = 0; si < 4; si++) {
    const int s = 4 * half + si;    // chunk index 0..7
    const float3 f = ((const float3*)src)[64 * s + lane];
    unsigned long long P0 = __ballot(f.x > 0.0f);
    unsigned long long N0 = __ballot(f.x < 0.0f);
    unsigned long long P1 = __ballot(f.y > 0.0f);
    unsigned long long N1 = __ballot(f.y < 0.0f);
    unsigned long long P2 = __ballot(f.z > 0.0f);
    unsigned long long N2 = __ballot(f.z < 0.0f);
    unsigned h0 = hi ? (unsigned)(P0 >> 32) : (unsigned)P0;
    unsigned h1 = hi ? (unsigned)(P1 >> 32) : (unsigned)P1;
    unsigned h2 = hi ? (unsigned)(P2 >> 32) : (unsigned)P2;
    unsigned h3 = hi ? (unsigned)(N0 >> 32) : (unsigned)N0;
    unsigned h4 = hi ? (unsigned)(N1 >> 32) : (unsigned)N1;
    unsigned h5 = hi ? (unsigned)(N2 >> 32) : (unsigned)N2;
    unsigned v01 = (j == 1) ? h1 : h0;
    unsigned v23 = (j == 3) ? h3 : h2;
    unsigned v45 = (j == 5) ? h5 : h4;
    unsigned val = (j < 2) ? v01 : ((j < 4) ? v23 : v45);
    if (lane < 12) packed[(size_t)row * 96 + s * 12 + lane] = val;
  }
}

// ---------------- main kernel ----------------
// 32 groups per call: cp = #(+1 products), cn = #(-1); contribution
// (cp>cn)+(cp>=cn) = sign+1. sum(sign) over 512 groups = acc_total - 512.
__device__ __forceinline__ void maj32(
    unsigned xp0, unsigned xp1, unsigned xp2,
    unsigned xn0, unsigned xn1, unsigned xn2,
    unsigned wp0, unsigned wp1, unsigned wp2,
    unsigned wn0, unsigned wn1, unsigned wn2,
    int& acc) {
  unsigned pos0 = (xp0 & wp0) | (xn0 & wn0);
  unsigned pos1 = (xp1 & wp1) | (xn1 & wn1);
  unsigned pos2 = (xp2 & wp2) | (xn2 & wn2);
  unsigned neg0 = (xp0 & wn0) | (xn0 & wp0);
  unsigned neg1 = (xp1 & wn1) | (xn1 & wp1);
  unsigned neg2 = (xp2 & wn2) | (xn2 & wp2);
  unsigned sa  = pos0 ^ pos1;
  unsigned cp0 = sa ^ pos2;
  unsigned cp1 = (pos0 & pos1) | (pos2 & sa);
  unsigned sb  = neg0 ^ neg1;
  unsigned cn0 = sb ^ neg2;
  unsigned cn1 = (neg0 & neg1) | (neg2 & sb);
  unsigned nh = ~cn1;
  unsigned nl = ~cn0;
  unsigned hi = cp1 & nh;
  unsigned eq = ~(cp1 ^ cn1);
  unsigned gt = hi | (eq & (cp0 & nl));
  unsigned ge = hi | (eq & (cp0 | nl));
  acc += __popc(gt) + __popc(ge);
}

// Process one chunk (3 uint4 per operand) for one (b,c) pair: both 32-group
// slices. Slice a = (.x,.z) lanes of the planes, slice b = (.y,.w).
__device__ __forceinline__ void chunk_bc(
    const uint4& a0, const uint4& a1, const uint4& a2,
    const uint4& b0, const uint4& b1, const uint4& b2,
    int& acc) {
  maj32(a0.x, a0.z, a1.x, a1.z, a2.x, a2.z,
        b0.x, b0.z, b1.x, b1.z, b2.x, b2.z, acc);
  maj32(a0.y, a0.w, a1.y, a1.w, a2.y, a2.w,
        b0.y, b0.w, b1.y, b1.w, b2.y, b2.w, acc);
}

// 16(b) x 16(c) tile, 256 threads, split-K 4 (wave = quarter = 2 chunks),
// thread = 2b x 2c micro-tile. grid = (32, 32) = 1024 blocks -> 4 blocks/CU
// -> 16 waves/CU. LDS = 2*16*25*16 + 4*256*4 = 16.9 KB.
__global__ __launch_bounds__(256, 4) void maj3_kernel(
    const uint4* __restrict__ px, const uint4* __restrict__ pw,
    float* __restrict__ out) {
  __shared__ __align__(16) uint4 sx[16][XSTRIDE];
  __shared__ __align__(16) uint4 sw[16][XSTRIDE];
  __shared__ int comb[4][256];

  const int b0 = blockIdx.y * 16;
  const int c0 = blockIdx.x * 16;
  const int tid = threadIdx.x;

  // stage 32 rows x 24 uint4: thread -> row tid>>3, 3 consecutive uint4 at
  // (tid&7)*3. 384B contiguous per row, rows dense in global -> coalesced.
  {
    const int r  = tid >> 3;           // 0..31
    const int wd = (tid & 7) * 3;      // 0..21
    const uint4* g = (r < 16) ? (px + (size_t)(b0 + r) * ROW_U4 + wd)
                              : (pw + (size_t)(c0 + r - 16) * ROW_U4 + wd);
    uint4* d = (r < 16) ? &sx[r][wd] : &sw[r - 16][wd];
    d[0] = g[0]; d[1] = g[1]; d[2] = g[2];
  }
  __syncthreads();

  const int t2c = tid & 7;         // c-pair index
  const int t2b = (tid >> 3) & 7;  // b-pair index
  const int q   = tid >> 6;        // K-quarter (= wave id): chunks [2q, 2q+2)

  const uint4* xr0 = &sx[2 * t2b][q * 6];
  const uint4* xr1 = &sx[2 * t2b + 1][q * 6];
  const uint4* wc0 = &sw[2 * t2c][q * 6];
  const uint4* wc1 = &sw[2 * t2c + 1][q * 6];

  int a00 = 0, a01 = 0, a10 = 0, a11 = 0;
  #pragma unroll
  for (int i = 0; i < 2; i++) {    // 2 chunks per quarter
    uint4 xa0 = xr0[3 * i], xa1 = xr0[3 * i + 1], xa2 = xr0[3 * i + 2];
    uint4 xb0 = xr1[3 * i], xb1 = xr1[3 * i + 1], xb2 = xr1[3 * i + 2];
    uint4 wa0 = wc0[3 * i], wa1 = wc0[3 * i + 1], wa2 = wc0[3 * i + 2];
    uint4 wb0 = wc1[3 * i], wb1 = wc1[3 * i + 1], wb2 = wc1[3 * i + 2];
    chunk_bc(xa0, xa1, xa2, wa0, wa1, wa2, a00);
    chunk_bc(xa0, xa1, xa2, wb0, wb1, wb2, a01);
    chunk_bc(xb0, xb1, xb2, wa0, wa1, wa2, a10);
    chunk_bc(xb0, xb1, xb2, wb0, wb1, wb2, a11);
  }

  // per-quarter partials (o = row-in-tile * 16 + col-in-tile)
  const int ob = 2 * t2b, oc = 2 * t2c;
  comb[q][ob * 16 + oc]           = a00;
  comb[q][ob * 16 + oc + 1]       = a01;
  comb[q][(ob + 1) * 16 + oc]     = a10;
  comb[q][(ob + 1) * 16 + oc + 1] = a11;
  __syncthreads();

  // combine: thread tid owns output tid; comb[q][tid] reads are 2-way (free)
  const int o = tid;
  int total = comb[0][o] + comb[1][o] + comb[2][o] + comb[3][o];
  // total = sum over 512 groups of (sign+1) -> sum(sign) = total - 512
  out[(size_t)(b0 + (o >> 4)) * COUT + c0 + (o & 15)] =
      2.25f * (float)(total - GROUPS);
}

extern "C" void kernel_launch(void* const* d_in, const int* in_sizes, int n_in,
                              void* d_out, int out_size, void* d_ws, size_t ws_size,
                              hipStream_t stream) {
  const float* x = (const float*)d_in[0];   // [512, 1536]
  const float* w = (const float*)d_in[1];   // [512, 1536]
  float* out = (float*)d_out;               // [512, 512]

  uint32_t* packed = (uint32_t*)d_ws;       // [1024][96] dwords = 384 KB
  const uint4* px = (const uint4*)packed;                        // rows 0..511 (x)
  const uint4* pw = (const uint4*)(packed + (size_t)B_DIM * 96); // rows 512..1023 (w)

  pack_kernel<<<512, 256, 0, stream>>>(x, w, packed);

  dim3 grid(COUT / 16, B_DIM / 16);
  maj3_kernel<<<grid, 256, 0, stream>>>(px, pw, out);
}